// Round 1
// baseline (797.751 us; speedup 1.0000x reference)
//
#include <hip/hip_runtime.h>
#include <stdint.h>

#define DM 1024
#define DF 4096
#define NE 8
#define NTOK 8192   // B*S = 4*2048

typedef __attribute__((ext_vector_type(8))) short short8;
typedef __attribute__((ext_vector_type(4))) float floatx4;

__device__ inline unsigned short f2bf(float f) {
    union { float f; unsigned u; } v; v.f = f;
    unsigned u = v.u;
    u += 0x7fffu + ((u >> 16) & 1u);   // round-to-nearest-even
    return (unsigned short)(u >> 16);
}

#define GLDS(g, l) __builtin_amdgcn_global_load_lds( \
    (const __attribute__((address_space(1))) void*)(g), \
    (__attribute__((address_space(3))) void*)(l), 16, 0, 0)

// ---------------- gating: one wave per token, fp64 accumulation ----------------
__global__ void gate_kernel(const float* __restrict__ x, const float* __restrict__ gw,
                            const float* __restrict__ gb, int* __restrict__ top1,
                            int* __restrict__ counts) {
    int t = blockIdx.x;
    int lane = threadIdx.x;            // 64 threads
    const float* xr = x + (size_t)t * DM;
    double acc[NE];
#pragma unroll
    for (int e = 0; e < NE; ++e) acc[e] = 0.0;
    for (int j = 0; j < DM / 64; ++j) {
        int d = j * 64 + lane;
        double xv = (double)xr[d];
        const float* g = gw + (size_t)d * NE;
#pragma unroll
        for (int e = 0; e < NE; ++e) acc[e] = fma(xv, (double)g[e], acc[e]);
    }
#pragma unroll
    for (int e = 0; e < NE; ++e) {
        for (int off = 32; off > 0; off >>= 1)
            acc[e] += __shfl_down(acc[e], off, 64);
    }
    if (lane == 0) {
        int best = 0;
        double bv = acc[0] + (double)gb[0];
        for (int e = 1; e < NE; ++e) {
            double v = acc[e] + (double)gb[e];
            if (v > bv) { bv = v; best = e; }   // strict > == first-max (jnp.argmax)
        }
        top1[t] = best;
        atomicAdd(&counts[best], 1);
    }
}

// ctrl layout (ints): [0..7] counts, [8..16] offsets (exclusive prefix + total), [17..24] cursor
__global__ void prefix_kernel(int* ctrl) {
    if (threadIdx.x == 0) {
        int s = 0;
        for (int e = 0; e < NE; ++e) { ctrl[8 + e] = s; ctrl[17 + e] = s; s += ctrl[e]; }
        ctrl[16] = s;
    }
}

__global__ void build_perm(const int* __restrict__ top1, int* __restrict__ ctrl,
                           int* __restrict__ perm) {
    int t = blockIdx.x * 256 + threadIdx.x;
    int e = top1[t];
    int p = atomicAdd(&ctrl[17 + e], 1);
    perm[p] = t;   // compacted position -> token id
}

// ---------------- fp32 -> bf16 convert (x) ----------------
__global__ void convert_x(const float* __restrict__ x, unsigned short* __restrict__ xb) {
    int i = blockIdx.x * 256 + threadIdx.x;     // over NTOK*DM/4
    const float4* x4 = (const float4*)x;
    float4 v = x4[i];
    ushort4 o;
    o.x = f2bf(v.x); o.y = f2bf(v.y); o.z = f2bf(v.z); o.w = f2bf(v.w);
    ((ushort4*)xb)[i] = o;
}

// ---------------- tiled transpose + convert: src [E][R][C] f32 -> dst [E][C][R] bf16 ----------------
__global__ void transpose_bf16(const float* __restrict__ src, unsigned short* __restrict__ dst,
                               int R, int C) {
    __shared__ float tile[64][65];
    int tilesR = R >> 6, tilesC = C >> 6;
    int bid = blockIdx.x;
    int e = bid / (tilesR * tilesC);
    int rem = bid % (tilesR * tilesC);
    int tr = rem / tilesC, tc = rem % tilesC;
    const float* s = src + (size_t)e * R * C + (size_t)(tr * 64) * C + tc * 64;
    unsigned short* d = dst + (size_t)e * R * C + (size_t)(tc * 64) * R + tr * 64;
    int tid = threadIdx.x;
#pragma unroll
    for (int i = 0; i < 16; ++i) {
        int idx = i * 256 + tid;
        int r = idx >> 6, c = idx & 63;
        tile[r][c] = s[(size_t)r * C + c];
    }
    __syncthreads();
#pragma unroll
    for (int i = 0; i < 16; ++i) {
        int idx = i * 256 + tid;
        int c = idx >> 6, r = idx & 63;
        d[(size_t)c * R + r] = f2bf(tile[r][c]);
    }
}

// ---------------- MFMA GEMM, m97 structure: 128x128 tile, BK=64, 4 waves (2x2 of 64x64) ----
// FFN1: H[off+r][:] = relu(x_bf16[perm[off+r]][:] @ w1t[e]^T + b1[e]),  K=1024, N=4096
// FFN2: out[perm[off+r]][:] = H[off+r][:] @ w2t[e]^T + b2[e],           K=4096, N=1024
template<bool FFN1>
__global__ __launch_bounds__(256) void ffn_gemm(
    const unsigned short* __restrict__ A,      // FFN1: xb [NTOK][DM]; FFN2: H [NTOK][DF]
    const unsigned short* __restrict__ Bt,     // FFN1: w1t [E][DF][DM]; FFN2: w2t [E][DM][DF]
    const float* __restrict__ bias,            // FFN1: b1 [E][DF]; FFN2: b2 [E][DM]
    const int* __restrict__ ctrl,
    const int* __restrict__ perm,
    unsigned short* __restrict__ Hout,
    float* __restrict__ Yout) {
    constexpr int K = FFN1 ? DM : DF;
    constexpr int N = FFN1 ? DF : DM;
    constexpr int NT = N / 128;
    constexpr int MT_MAX = NTOK / 128;

    int bid = blockIdx.x;
    int e = bid / (MT_MAX * NT);
    int rem = bid % (MT_MAX * NT);
    int mt = rem / NT;
    int nt = rem % NT;

    int off = ctrl[8 + e];
    int ne  = ctrl[9 + e] - off;
    if (mt * 128 >= ne) return;

    __shared__ __align__(16) unsigned short As[128 * 64];
    __shared__ __align__(16) unsigned short Bs[128 * 64];

    int tid = threadIdx.x;
    int lane = tid & 63;
    int wave = tid >> 6;
    int wm = (wave & 1) * 64;
    int wn = (wave >> 1) * 64;

    // per-thread staging source pointers (4 chunks of 16B each for A and B)
    const unsigned short* arow[4];
#pragma unroll
    for (int i = 0; i < 4; ++i) {
        int c = i * 256 + tid;            // chunk 0..1023; row = c>>3, kchunk = c&7
        int r = c >> 3;
        int gr = mt * 128 + r;
        int rr = gr < ne ? gr : ne - 1;   // clamp partial tile (duplicate a valid row)
        int srow = FFN1 ? perm[off + rr] : (off + rr);
        arow[i] = A + (size_t)srow * K + (c & 7) * 8;
    }
    const unsigned short* bbase = Bt + (size_t)e * N * K + (size_t)(nt * 128) * K;
    const unsigned short* brow[4];
#pragma unroll
    for (int i = 0; i < 4; ++i) {
        int c = i * 256 + tid;
        brow[i] = bbase + (size_t)(c >> 3) * K + (c & 7) * 8;
    }

    floatx4 acc[4][4];
#pragma unroll
    for (int i = 0; i < 4; ++i)
#pragma unroll
        for (int j = 0; j < 4; ++j) acc[i][j] = floatx4{0.f, 0.f, 0.f, 0.f};

    for (int kk = 0; kk < K; kk += 64) {
#pragma unroll
        for (int i = 0; i < 4; ++i) {
            int c = i * 256 + tid;
            GLDS(arow[i] + kk, &As[c * 8]);
            GLDS(brow[i] + kk, &Bs[c * 8]);
        }
        __syncthreads();
#pragma unroll
        for (int ks = 0; ks < 2; ++ks) {
            short8 af[4], bf[4];
#pragma unroll
            for (int m = 0; m < 4; ++m)
                af[m] = *(const short8*)&As[(wm + m * 16 + (lane & 15)) * 64 + ks * 32 + (lane >> 4) * 8];
#pragma unroll
            for (int n = 0; n < 4; ++n)
                bf[n] = *(const short8*)&Bs[(wn + n * 16 + (lane & 15)) * 64 + ks * 32 + (lane >> 4) * 8];
#pragma unroll
            for (int m = 0; m < 4; ++m)
#pragma unroll
                for (int n = 0; n < 4; ++n)
                    acc[m][n] = __builtin_amdgcn_mfma_f32_16x16x32_bf16(af[m], bf[n], acc[m][n], 0, 0, 0);
        }
        __syncthreads();
    }

    // epilogue; C/D layout: col = lane&15, row = (lane>>4)*4 + reg
    int col0 = nt * 128 + wn + (lane & 15);
    int rowq = (lane >> 4) * 4;
    float bv[4];
#pragma unroll
    for (int n = 0; n < 4; ++n) bv[n] = bias[e * N + col0 + n * 16];

#pragma unroll
    for (int m = 0; m < 4; ++m) {
#pragma unroll
        for (int r = 0; r < 4; ++r) {
            int gr = mt * 128 + wm + m * 16 + rowq + r;
            if (gr < ne) {
                if (FFN1) {
                    unsigned short* hr = Hout + (size_t)(off + gr) * DF + col0;
#pragma unroll
                    for (int n = 0; n < 4; ++n) {
                        float v = acc[m][n][r] + bv[n];
                        v = v > 0.f ? v : 0.f;
                        hr[n * 16] = f2bf(v);
                    }
                } else {
                    float* yr = Yout + (size_t)perm[off + gr] * DM + col0;
#pragma unroll
                    for (int n = 0; n < 4; ++n)
                        yr[n * 16] = acc[m][n][r] + bv[n];
                }
            }
        }
    }
}

extern "C" void kernel_launch(void* const* d_in, const int* in_sizes, int n_in,
                              void* d_out, int out_size, void* d_ws, size_t ws_size,
                              hipStream_t stream) {
    const float* x  = (const float*)d_in[0];
    const float* w1 = (const float*)d_in[1];
    const float* b1 = (const float*)d_in[2];
    const float* w2 = (const float*)d_in[3];
    const float* b2 = (const float*)d_in[4];
    const float* gw = (const float*)d_in[5];
    const float* gb = (const float*)d_in[6];
    float* out = (float*)d_out;

    // workspace carve-up
    char* ws = (char*)d_ws;
    int* ctrl = (int*)ws;                                   // 1 KiB control block
    int* top1 = (int*)(ws + 1024);                          // 8192 ints
    int* perm = (int*)(ws + 1024 + 32768);                  // 8192 ints
    size_t o = 66560;                                       // 256B-aligned
    unsigned short* xb  = (unsigned short*)(ws + o);        o += (size_t)NTOK * DM * 2;      // 16.8 MB
    unsigned short* w1t = (unsigned short*)(ws + o);        o += (size_t)NE * DM * DF * 2;   // 67 MB
    unsigned short* w2t = (unsigned short*)(ws + o);        o += (size_t)NE * DM * DF * 2;   // 67 MB
    unsigned short* H   = (unsigned short*)(ws + o);        // 67 MB  (total ~218 MB)

    hipMemsetAsync(ctrl, 0, 1024, stream);
    gate_kernel<<<NTOK, 64, 0, stream>>>(x, gw, gb, top1, ctrl);
    prefix_kernel<<<1, 64, 0, stream>>>(ctrl);
    build_perm<<<NTOK / 256, 256, 0, stream>>>(top1, ctrl, perm);
    convert_x<<<NTOK * DM / 4 / 256, 256, 0, stream>>>(x, xb);
    transpose_bf16<<<NE * (DM / 64) * (DF / 64), 256, 0, stream>>>(w1, w1t, DM, DF);
    transpose_bf16<<<NE * (DF / 64) * (DM / 64), 256, 0, stream>>>(w2, w2t, DF, DM);
    ffn_gemm<true ><<<NE * (NTOK / 128) * (DF / 128), 256, 0, stream>>>(xb, w1t, b1, ctrl, perm, H, nullptr);
    ffn_gemm<false><<<NE * (NTOK / 128) * (DM / 128), 256, 0, stream>>>(H, w2t, b2, ctrl, perm, nullptr, out);
}

// Round 2
// 760.397 us; speedup vs baseline: 1.0491x; 1.0491x over previous
//
#include <hip/hip_runtime.h>
#include <stdint.h>

#define DM 1024
#define DF 4096
#define NE 8
#define NTOK 8192   // B*S = 4*2048
#define MT_LAUNCH 72  // >= max total m-tiles (71), divisible by swizzle group G=8

typedef __attribute__((ext_vector_type(8))) short short8;
typedef __attribute__((ext_vector_type(8))) unsigned short ushort8v;
typedef __attribute__((ext_vector_type(4))) float floatx4;

__device__ inline unsigned short f2bf(float f) {
    union { float f; unsigned u; } v; v.f = f;
    unsigned u = v.u;
    u += 0x7fffu + ((u >> 16) & 1u);   // round-to-nearest-even
    return (unsigned short)(u >> 16);
}

#define GLDS(g, l) __builtin_amdgcn_global_load_lds( \
    (const __attribute__((address_space(1))) void*)(g), \
    (__attribute__((address_space(3))) void*)(l), 16, 0, 0)

// ---------------- gating: one wave per token, fp64 accumulation ----------------
__global__ void gate_kernel(const float* __restrict__ x, const float* __restrict__ gw,
                            const float* __restrict__ gb, int* __restrict__ top1,
                            int* __restrict__ counts) {
    int t = blockIdx.x;
    int lane = threadIdx.x;            // 64 threads
    const float* xr = x + (size_t)t * DM;
    double acc[NE];
#pragma unroll
    for (int e = 0; e < NE; ++e) acc[e] = 0.0;
    for (int j = 0; j < DM / 64; ++j) {
        int d = j * 64 + lane;
        double xv = (double)xr[d];
        const float* g = gw + (size_t)d * NE;
#pragma unroll
        for (int e = 0; e < NE; ++e) acc[e] = fma(xv, (double)g[e], acc[e]);
    }
#pragma unroll
    for (int e = 0; e < NE; ++e) {
        for (int off = 32; off > 0; off >>= 1)
            acc[e] += __shfl_down(acc[e], off, 64);
    }
    if (lane == 0) {
        int best = 0;
        double bv = acc[0] + (double)gb[0];
        for (int e = 1; e < NE; ++e) {
            double v = acc[e] + (double)gb[e];
            if (v > bv) { bv = v; best = e; }   // strict > == first-max (jnp.argmax)
        }
        top1[t] = best;
        atomicAdd(&counts[best], 1);
    }
}

// ctrl ints: [0..7] counts, [8..16] offsets (+total), [17..24] cursors, [25] ntiles,
//            [32+3i..] tile table: (expert, compacted rowbase, rows)
__global__ void prefix_kernel(int* ctrl) {
    if (threadIdx.x == 0) {
        int s = 0, t = 0;
        for (int e = 0; e < NE; ++e) {
            int cnt = ctrl[e];
            ctrl[8 + e] = s; ctrl[17 + e] = s;
            for (int m = 0; m * 128 < cnt; ++m) {
                ctrl[32 + 3 * t] = e;
                ctrl[33 + 3 * t] = s + m * 128;
                int rr = cnt - m * 128;
                ctrl[34 + 3 * t] = rr < 128 ? rr : 128;
                ++t;
            }
            s += cnt;
        }
        ctrl[16] = s;
        ctrl[25] = t;
    }
}

__global__ void build_perm(const int* __restrict__ top1, int* __restrict__ ctrl,
                           int* __restrict__ perm) {
    int t = blockIdx.x * 256 + threadIdx.x;
    int e = top1[t];
    int p = atomicAdd(&ctrl[17 + e], 1);
    perm[p] = t;   // compacted position -> token id
}

// ---------------- fp32 -> bf16 convert (x) ----------------
__global__ void convert_x(const float* __restrict__ x, unsigned short* __restrict__ xb) {
    int i = blockIdx.x * 256 + threadIdx.x;     // over NTOK*DM/4
    const float4* x4 = (const float4*)x;
    float4 v = x4[i];
    ushort4 o;
    o.x = f2bf(v.x); o.y = f2bf(v.y); o.z = f2bf(v.z); o.w = f2bf(v.w);
    ((ushort4*)xb)[i] = o;
}

// -------- tiled transpose + convert: src [E][R][C] f32 -> dst [E][C][R] bf16 --------
// float4 global loads; 16B ushort8 stores. +65 padding: LDS accesses 2-way max (free).
__global__ void transpose_bf16(const float* __restrict__ src, unsigned short* __restrict__ dst,
                               int R, int C) {
    __shared__ float tile[64][65];
    int tilesR = R >> 6, tilesC = C >> 6;
    int bid = blockIdx.x;
    int e = bid / (tilesR * tilesC);
    int rem = bid % (tilesR * tilesC);
    int tr = rem / tilesC, tc = rem % tilesC;
    const float* s = src + (size_t)e * R * C + (size_t)(tr * 64) * C + tc * 64;
    unsigned short* d = dst + (size_t)e * R * C + (size_t)(tc * 64) * R + tr * 64;
    int tid = threadIdx.x;
#pragma unroll
    for (int i = 0; i < 4; ++i) {
        int idx = i * 256 + tid;          // 0..1023
        int r = idx >> 4, c4 = (idx & 15) * 4;
        float4 v = *(const float4*)(s + (size_t)r * C + c4);
        tile[r][c4 + 0] = v.x; tile[r][c4 + 1] = v.y;
        tile[r][c4 + 2] = v.z; tile[r][c4 + 3] = v.w;
    }
    __syncthreads();
#pragma unroll
    for (int i = 0; i < 2; ++i) {
        int idx = i * 256 + tid;          // 0..511
        int c = idx >> 3, r8 = (idx & 7) * 8;
        ushort8v o;
#pragma unroll
        for (int j = 0; j < 8; ++j) o[j] = f2bf(tile[r8 + j][c]);
        *(ushort8v*)(d + (size_t)c * R + r8) = o;
    }
}

// ---------------- MFMA GEMM over the m-tile table ----------------
// FFN1: 128x128 tile; H[cr][:] = relu(xb[perm[cr]][:] @ w1t[e]^T + b1[e]),  K=1024, N=4096
// FFN2: 128x64 tile;  out[perm[cr]][:] = H[cr][:] @ w2t[e]^T + b2[e],       K=4096, N=1024
template<bool FFN1>
__global__ __launch_bounds__(256) void ffn_gemm(
    const unsigned short* __restrict__ A,
    const unsigned short* __restrict__ Bt,
    const float* __restrict__ bias,
    const int* __restrict__ ctrl,
    const int* __restrict__ perm,
    unsigned short* __restrict__ Hout,
    float* __restrict__ Yout) {
    constexpr int K  = FFN1 ? DM : DF;
    constexpr int N  = FFN1 ? DF : DM;
    constexpr int TN = FFN1 ? 128 : 64;     // N-tile
    constexpr int NT = N / TN;              // 32 / 16
    constexpr int NF = TN / 32;             // n-frags per wave: 4 / 2
    constexpr int BCH = TN * 8 / 256;       // B 16B-chunks per thread: 4 / 2
    constexpr int G = 8;                    // m-tiles per swizzle group

    // swizzle: in-flight window covers G m-tiles x NT n-tiles -> A and B both reused
    int b = blockIdx.x;
    int grp = b / (G * NT);
    int ii = b % (G * NT);
    int nt = ii % NT;
    int til = grp * G + ii / NT;
    if (til >= ctrl[25]) return;
    int e       = ctrl[32 + 3 * til];
    int rowbase = ctrl[33 + 3 * til];
    int rows    = ctrl[34 + 3 * til];

    __shared__ __align__(16) unsigned short As[128 * 64];
    __shared__ __align__(16) unsigned short Bs[TN * 64];

    int tid = threadIdx.x;
    int lane = tid & 63;
    int wave = tid >> 6;
    int wm = (wave & 1) * 64;
    int wn = (wave >> 1) * (NF * 16);

    const unsigned short* arow[4];
#pragma unroll
    for (int i = 0; i < 4; ++i) {
        int c = i * 256 + tid;            // chunk; row = c>>3, kchunk = c&7
        int r = c >> 3;
        int rr = r < rows ? r : rows - 1; // clamp partial tile
        int cr = rowbase + rr;
        int srow = FFN1 ? perm[cr] : cr;
        arow[i] = A + (size_t)srow * K + (c & 7) * 8;
    }
    const unsigned short* bbase = Bt + (size_t)e * N * K + (size_t)(nt * TN) * K;
    const unsigned short* brow[BCH];
#pragma unroll
    for (int i = 0; i < BCH; ++i) {
        int c = i * 256 + tid;
        brow[i] = bbase + (size_t)(c >> 3) * K + (c & 7) * 8;
    }

    floatx4 acc[4][NF];
#pragma unroll
    for (int i = 0; i < 4; ++i)
#pragma unroll
        for (int j = 0; j < NF; ++j) acc[i][j] = floatx4{0.f, 0.f, 0.f, 0.f};

    for (int kk = 0; kk < K; kk += 64) {
#pragma unroll
        for (int i = 0; i < 4; ++i) GLDS(arow[i] + kk, &As[(i * 256 + tid) * 8]);
#pragma unroll
        for (int i = 0; i < BCH; ++i) GLDS(brow[i] + kk, &Bs[(i * 256 + tid) * 8]);
        __syncthreads();
#pragma unroll
        for (int ks = 0; ks < 2; ++ks) {
            short8 af[4], bfr[NF];
#pragma unroll
            for (int m = 0; m < 4; ++m)
                af[m] = *(const short8*)&As[(wm + m * 16 + (lane & 15)) * 64 + ks * 32 + (lane >> 4) * 8];
#pragma unroll
            for (int n = 0; n < NF; ++n)
                bfr[n] = *(const short8*)&Bs[(wn + n * 16 + (lane & 15)) * 64 + ks * 32 + (lane >> 4) * 8];
#pragma unroll
            for (int m = 0; m < 4; ++m)
#pragma unroll
                for (int n = 0; n < NF; ++n)
                    acc[m][n] = __builtin_amdgcn_mfma_f32_16x16x32_bf16(af[m], bfr[n], acc[m][n], 0, 0, 0);
        }
        __syncthreads();
    }

    // epilogue; C/D layout: col = lane&15, row = (lane>>4)*4 + reg
    int col0 = nt * TN + wn + (lane & 15);
    int rowq = (lane >> 4) * 4;
    float bv[NF];
#pragma unroll
    for (int n = 0; n < NF; ++n) bv[n] = bias[e * N + col0 + n * 16];

#pragma unroll
    for (int m = 0; m < 4; ++m) {
#pragma unroll
        for (int r = 0; r < 4; ++r) {
            int lr = wm + m * 16 + rowq + r;
            if (lr < rows) {
                if (FFN1) {
                    unsigned short* hr = Hout + (size_t)(rowbase + lr) * DF + col0;
#pragma unroll
                    for (int n = 0; n < NF; ++n) {
                        float v = acc[m][n][r] + bv[n];
                        v = v > 0.f ? v : 0.f;
                        hr[n * 16] = f2bf(v);
                    }
                } else {
                    float* yr = Yout + (size_t)perm[rowbase + lr] * DM + col0;
#pragma unroll
                    for (int n = 0; n < NF; ++n)
                        yr[n * 16] = acc[m][n][r] + bv[n];
                }
            }
        }
    }
}

extern "C" void kernel_launch(void* const* d_in, const int* in_sizes, int n_in,
                              void* d_out, int out_size, void* d_ws, size_t ws_size,
                              hipStream_t stream) {
    const float* x  = (const float*)d_in[0];
    const float* w1 = (const float*)d_in[1];
    const float* b1 = (const float*)d_in[2];
    const float* w2 = (const float*)d_in[3];
    const float* b2 = (const float*)d_in[4];
    const float* gw = (const float*)d_in[5];
    const float* gb = (const float*)d_in[6];
    float* out = (float*)d_out;

    // workspace carve-up
    char* ws = (char*)d_ws;
    int* ctrl = (int*)ws;                                   // 1 KiB control block
    int* top1 = (int*)(ws + 1024);                          // 8192 ints
    int* perm = (int*)(ws + 1024 + 32768);                  // 8192 ints
    size_t o = 66560;                                       // 256B-aligned
    unsigned short* xb  = (unsigned short*)(ws + o);        o += (size_t)NTOK * DM * 2;      // 16.8 MB
    unsigned short* w1t = (unsigned short*)(ws + o);        o += (size_t)NE * DM * DF * 2;   // 67 MB
    unsigned short* w2t = (unsigned short*)(ws + o);        o += (size_t)NE * DM * DF * 2;   // 67 MB
    unsigned short* H   = (unsigned short*)(ws + o);        // 67 MB  (total ~218 MB)

    hipMemsetAsync(ctrl, 0, 1024, stream);
    gate_kernel<<<NTOK, 64, 0, stream>>>(x, gw, gb, top1, ctrl);
    prefix_kernel<<<1, 64, 0, stream>>>(ctrl);
    build_perm<<<NTOK / 256, 256, 0, stream>>>(top1, ctrl, perm);
    convert_x<<<NTOK * DM / 4 / 256, 256, 0, stream>>>(x, xb);
    transpose_bf16<<<NE * (DM / 64) * (DF / 64), 256, 0, stream>>>(w1, w1t, DM, DF);
    transpose_bf16<<<NE * (DF / 64) * (DM / 64), 256, 0, stream>>>(w2, w2t, DF, DM);
    ffn_gemm<true ><<<MT_LAUNCH * (DF / 128), 256, 0, stream>>>(xb, w1t, b1, ctrl, perm, H, nullptr);
    ffn_gemm<false><<<MT_LAUNCH * (DM / 64), 256, 0, stream>>>(H, w2t, b2, ctrl, perm, nullptr, out);
}

// Round 3
// 679.072 us; speedup vs baseline: 1.1748x; 1.1198x over previous
//
#include <hip/hip_runtime.h>
#include <stdint.h>

#define DM 1024
#define DF 4096
#define NE 8
#define NTOK 8192   // B*S = 4*2048
#define MT_LAUNCH 72  // >= max total m-tiles (71), divisible by swizzle group G=8

typedef __attribute__((ext_vector_type(8))) short short8;
typedef __attribute__((ext_vector_type(8))) unsigned short ushort8v;
typedef __attribute__((ext_vector_type(4))) float floatx4;

__device__ inline unsigned short f2bf(float f) {
    union { float f; unsigned u; } v; v.f = f;
    unsigned u = v.u;
    u += 0x7fffu + ((u >> 16) & 1u);   // round-to-nearest-even
    return (unsigned short)(u >> 16);
}

#define GLDS(g, l) __builtin_amdgcn_global_load_lds( \
    (const __attribute__((address_space(1))) void*)(g), \
    (__attribute__((address_space(3))) void*)(l), 16, 0, 0)

// ---------------- gating: one wave per token, fp64 accumulation, no atomics ----------------
__global__ void gate_kernel(const float* __restrict__ x, const float* __restrict__ gw,
                            const float* __restrict__ gb, int* __restrict__ top1) {
    int t = blockIdx.x;
    int lane = threadIdx.x;            // 64 threads
    const float* xr = x + (size_t)t * DM;
    double acc[NE];
#pragma unroll
    for (int e = 0; e < NE; ++e) acc[e] = 0.0;
    for (int j = 0; j < DM / 64; ++j) {
        int d = j * 64 + lane;
        double xv = (double)xr[d];
        const float* g = gw + (size_t)d * NE;
#pragma unroll
        for (int e = 0; e < NE; ++e) acc[e] = fma(xv, (double)g[e], acc[e]);
    }
#pragma unroll
    for (int e = 0; e < NE; ++e) {
        for (int off = 32; off > 0; off >>= 1)
            acc[e] += __shfl_down(acc[e], off, 64);
    }
    if (lane == 0) {
        int best = 0;
        double bv = acc[0] + (double)gb[0];
        for (int e = 1; e < NE; ++e) {
            double v = acc[e] + (double)gb[e];
            if (v > bv) { bv = v; best = e; }   // strict > == first-max (jnp.argmax)
        }
        top1[t] = best;
    }
}

// ctrl ints: [0..7] counts, [8..16] offsets (+total), [17..24] cursors, [25] ntiles,
//            [32+3i..] tile table: (expert, compacted rowbase, rows)
__global__ void count_kernel(const int* __restrict__ top1, int* __restrict__ ctrl) {
    int t = blockIdx.x * 256 + threadIdx.x;
    int e = top1[t];
    int lane = threadIdx.x & 63;
#pragma unroll
    for (int ex = 0; ex < NE; ++ex) {
        unsigned long long m = __ballot(e == ex);
        if (m != 0ull && lane == (__ffsll((long long)m) - 1))
            atomicAdd(&ctrl[ex], __popcll(m));
    }
}

__global__ void prefix_kernel(int* ctrl) {
    if (threadIdx.x == 0) {
        int s = 0, t = 0;
        for (int e = 0; e < NE; ++e) {
            int cnt = ctrl[e];
            ctrl[8 + e] = s; ctrl[17 + e] = s;
            for (int m = 0; m * 128 < cnt; ++m) {
                ctrl[32 + 3 * t] = e;
                ctrl[33 + 3 * t] = s + m * 128;
                int rr = cnt - m * 128;
                ctrl[34 + 3 * t] = rr < 128 ? rr : 128;
                ++t;
            }
            s += cnt;
        }
        ctrl[16] = s;
        ctrl[25] = t;
    }
}

__global__ void scatter_kernel(const int* __restrict__ top1, int* __restrict__ ctrl,
                               int* __restrict__ perm) {
    int t = blockIdx.x * 256 + threadIdx.x;
    int e = top1[t];
    int lane = threadIdx.x & 63;
#pragma unroll
    for (int ex = 0; ex < NE; ++ex) {
        unsigned long long m = __ballot(e == ex);
        if (m == 0ull) continue;
        int leader = __ffsll((long long)m) - 1;
        int base = 0;
        if (lane == leader) base = atomicAdd(&ctrl[17 + ex], __popcll(m));
        base = __shfl(base, leader, 64);
        if (e == ex) {
            int pos = __popcll(m & ((1ull << lane) - 1ull));
            perm[base + pos] = t;   // compacted position -> token id
        }
    }
}

// ---------------- fp32 -> bf16 convert (x) ----------------
__global__ void convert_x(const float* __restrict__ x, unsigned short* __restrict__ xb) {
    int i = blockIdx.x * 256 + threadIdx.x;     // over NTOK*DM/4
    const float4* x4 = (const float4*)x;
    float4 v = x4[i];
    ushort4 o;
    o.x = f2bf(v.x); o.y = f2bf(v.y); o.z = f2bf(v.z); o.w = f2bf(v.w);
    ((ushort4*)xb)[i] = o;
}

// -------- tiled transpose + convert: src [E][R][C] f32 -> dst [E][C][R] bf16 --------
__global__ void transpose_bf16(const float* __restrict__ src, unsigned short* __restrict__ dst,
                               int R, int C) {
    __shared__ float tile[64][65];
    int tilesR = R >> 6, tilesC = C >> 6;
    int bid = blockIdx.x;
    int e = bid / (tilesR * tilesC);
    int rem = bid % (tilesR * tilesC);
    int tr = rem / tilesC, tc = rem % tilesC;
    const float* s = src + (size_t)e * R * C + (size_t)(tr * 64) * C + tc * 64;
    unsigned short* d = dst + (size_t)e * R * C + (size_t)(tc * 64) * R + tr * 64;
    int tid = threadIdx.x;
#pragma unroll
    for (int i = 0; i < 4; ++i) {
        int idx = i * 256 + tid;          // 0..1023
        int r = idx >> 4, c4 = (idx & 15) * 4;
        float4 v = *(const float4*)(s + (size_t)r * C + c4);
        tile[r][c4 + 0] = v.x; tile[r][c4 + 1] = v.y;
        tile[r][c4 + 2] = v.z; tile[r][c4 + 3] = v.w;
    }
    __syncthreads();
#pragma unroll
    for (int i = 0; i < 2; ++i) {
        int idx = i * 256 + tid;          // 0..511
        int c = idx >> 3, r8 = (idx & 7) * 8;
        ushort8v o;
#pragma unroll
        for (int j = 0; j < 8; ++j) o[j] = f2bf(tile[r8 + j][c]);
        *(ushort8v*)(d + (size_t)c * R + r8) = o;
    }
}

// ---------------- MFMA GEMM over the m-tile table, XOR-swizzled LDS ----------------
// LDS layout: row r's k-chunk gk (8 bf16 = 16B) lives at slot s = gk ^ (r&7).
// Staging: GLDS global addr is per-lane, so lane fetches chunk (slot ^ (r&7)); LDS dest stays
// contiguous (wave-uniform base + lane*16). Fragment ds_read_b128: addr = r*128B + s*16B ->
// banks 4s..4s+3, s a permutation of 0..7 over the quad's 16 lanes -> 2-way (free).
// FFN1: 128x128, K=1024;   H = relu(xb[perm] @ w1t^T + b1), bf16 out
// FFN2: 128x128, K=4096 split-K x2; out[perm] += H @ w2t^T (+ b2 on split 0), fp32 atomics
template<bool FFN1>
__global__ __launch_bounds__(256) void ffn_gemm(
    const unsigned short* __restrict__ A,
    const unsigned short* __restrict__ Bt,
    const float* __restrict__ bias,
    const int* __restrict__ ctrl,
    const int* __restrict__ perm,
    unsigned short* __restrict__ Hout,
    float* __restrict__ Yout) {
    constexpr int K  = FFN1 ? DM : DF;
    constexpr int N  = FFN1 ? DF : DM;
    constexpr int KS = FFN1 ? 1 : 2;        // split-K factor
    constexpr int KLEN = K / KS;
    constexpr int NT = N / 128;             // 32 / 8
    constexpr int G = 8;                    // m-tiles per swizzle group
    constexpr int INNER = NT * KS;          // blocks per m-tile

    int b = blockIdx.x;
    int grp = b / (G * INNER);
    int ii = b % (G * INNER);
    int til = grp * G + ii / INNER;
    int r2 = ii % INNER;
    int nt = r2 / KS;
    int ksp = r2 % KS;
    if (til >= ctrl[25]) return;
    int e       = ctrl[32 + 3 * til];
    int rowbase = ctrl[33 + 3 * til];
    int rows    = ctrl[34 + 3 * til];

    __shared__ __align__(16) unsigned short As[128 * 64];
    __shared__ __align__(16) unsigned short Bs[128 * 64];

    int tid = threadIdx.x;
    int lane = tid & 63;
    int wave = tid >> 6;
    int wm = (wave & 1) * 64;
    int wn = (wave >> 1) * 64;

    // staging source pointers: LDS chunk c = r*8 + slot; global chunk gk = slot ^ (r&7)
    const unsigned short* arow[4];
    const unsigned short* brow[4];
    const unsigned short* bbase = Bt + (size_t)e * N * K + (size_t)(nt * 128) * K;
#pragma unroll
    for (int i = 0; i < 4; ++i) {
        int c = i * 256 + tid;
        int r = c >> 3;
        int gk = (c & 7) ^ (r & 7);
        int rr = r < rows ? r : rows - 1;   // clamp partial tile
        int cr = rowbase + rr;
        int srow = FFN1 ? perm[cr] : cr;
        arow[i] = A + (size_t)srow * K + gk * 8;
        brow[i] = bbase + (size_t)r * K + gk * 8;
    }

    floatx4 acc[4][4];
#pragma unroll
    for (int i = 0; i < 4; ++i)
#pragma unroll
        for (int j = 0; j < 4; ++j) acc[i][j] = floatx4{0.f, 0.f, 0.f, 0.f};

    for (int kk = ksp * KLEN; kk < ksp * KLEN + KLEN; kk += 64) {
#pragma unroll
        for (int i = 0; i < 4; ++i) {
            GLDS(arow[i] + kk, &As[(i * 256 + tid) * 8]);
            GLDS(brow[i] + kk, &Bs[(i * 256 + tid) * 8]);
        }
        __syncthreads();
#pragma unroll
        for (int ks = 0; ks < 2; ++ks) {
            short8 af[4], bfr[4];
#pragma unroll
            for (int m = 0; m < 4; ++m) {
                int R = wm + m * 16 + (lane & 15);
                int s = (ks * 4 + (lane >> 4)) ^ (R & 7);
                af[m] = *(const short8*)&As[R * 64 + s * 8];
            }
#pragma unroll
            for (int n = 0; n < 4; ++n) {
                int R = wn + n * 16 + (lane & 15);
                int s = (ks * 4 + (lane >> 4)) ^ (R & 7);
                bfr[n] = *(const short8*)&Bs[R * 64 + s * 8];
            }
#pragma unroll
            for (int m = 0; m < 4; ++m)
#pragma unroll
                for (int n = 0; n < 4; ++n)
                    acc[m][n] = __builtin_amdgcn_mfma_f32_16x16x32_bf16(af[m], bfr[n], acc[m][n], 0, 0, 0);
        }
        __syncthreads();
    }

    // epilogue; C/D layout: col = lane&15, row = (lane>>4)*4 + reg
    int col0 = nt * 128 + wn + (lane & 15);
    int rowq = (lane >> 4) * 4;
    float bv[4];
#pragma unroll
    for (int n = 0; n < 4; ++n) bv[n] = (FFN1 || ksp == 0) ? bias[e * N + col0 + n * 16] : 0.f;

#pragma unroll
    for (int m = 0; m < 4; ++m) {
#pragma unroll
        for (int r = 0; r < 4; ++r) {
            int lr = wm + m * 16 + rowq + r;
            if (lr < rows) {
                if (FFN1) {
                    unsigned short* hr = Hout + (size_t)(rowbase + lr) * DF + col0;
#pragma unroll
                    for (int n = 0; n < 4; ++n) {
                        float v = acc[m][n][r] + bv[n];
                        v = v > 0.f ? v : 0.f;
                        hr[n * 16] = f2bf(v);
                    }
                } else {
                    float* yr = Yout + (size_t)perm[rowbase + lr] * DM + col0;
#pragma unroll
                    for (int n = 0; n < 4; ++n)
                        atomicAdd(&yr[n * 16], acc[m][n][r] + bv[n]);
                }
            }
        }
    }
}

extern "C" void kernel_launch(void* const* d_in, const int* in_sizes, int n_in,
                              void* d_out, int out_size, void* d_ws, size_t ws_size,
                              hipStream_t stream) {
    const float* x  = (const float*)d_in[0];
    const float* w1 = (const float*)d_in[1];
    const float* b1 = (const float*)d_in[2];
    const float* w2 = (const float*)d_in[3];
    const float* b2 = (const float*)d_in[4];
    const float* gw = (const float*)d_in[5];
    const float* gb = (const float*)d_in[6];
    float* out = (float*)d_out;

    // workspace carve-up
    char* ws = (char*)d_ws;
    int* ctrl = (int*)ws;                                   // 1 KiB control block
    int* top1 = (int*)(ws + 1024);                          // 8192 ints
    int* perm = (int*)(ws + 1024 + 32768);                  // 8192 ints
    size_t o = 66560;                                       // 256B-aligned
    unsigned short* xb  = (unsigned short*)(ws + o);        o += (size_t)NTOK * DM * 2;      // 16.8 MB
    unsigned short* w1t = (unsigned short*)(ws + o);        o += (size_t)NE * DM * DF * 2;   // 67 MB
    unsigned short* w2t = (unsigned short*)(ws + o);        o += (size_t)NE * DM * DF * 2;   // 67 MB
    unsigned short* H   = (unsigned short*)(ws + o);        // 67 MB  (total ~218 MB)

    hipMemsetAsync(ctrl, 0, 1024, stream);
    hipMemsetAsync(out, 0, (size_t)out_size * 4, stream);   // required: FFN2 accumulates atomically
    gate_kernel<<<NTOK, 64, 0, stream>>>(x, gw, gb, top1);
    count_kernel<<<NTOK / 256, 256, 0, stream>>>(top1, ctrl);
    prefix_kernel<<<1, 64, 0, stream>>>(ctrl);
    scatter_kernel<<<NTOK / 256, 256, 0, stream>>>(top1, ctrl, perm);
    convert_x<<<NTOK * DM / 4 / 256, 256, 0, stream>>>(x, xb);
    transpose_bf16<<<NE * (DM / 64) * (DF / 64), 256, 0, stream>>>(w1, w1t, DM, DF);
    transpose_bf16<<<NE * (DF / 64) * (DM / 64), 256, 0, stream>>>(w2, w2t, DF, DM);
    ffn_gemm<true ><<<MT_LAUNCH * (DF / 128), 256, 0, stream>>>(xb, w1t, b1, ctrl, perm, H, nullptr);
    ffn_gemm<false><<<MT_LAUNCH * (DM / 128) * 2, 256, 0, stream>>>(H, w2t, b2, ctrl, perm, nullptr, out);
}